// Round 1
// baseline (19413.744 us; speedup 1.0000x reference)
//
#include <hip/hip_runtime.h>
#include <stdint.h>

// LSTM: B=32, S=1024, I=512, H=512, 4H=2048
//
// Phase 1: x_gates = x @ W_ih^T + (b_ih + b_hh)   [bf16 MFMA GEMM, 68.7 GFLOP]
// Phase 2: persistent cooperative kernel, 8 groups x 32 WGs; each group owns 4
//          batches; per-WG W_hh slice (64 gate rows) in REGISTERS (128 fp32/thr),
//          h staged in LDS, h exchanged via global double buffer + per-group
//          monotonic barrier (agent-scope atomics).

typedef __attribute__((ext_vector_type(8))) short bf16x8;
typedef __attribute__((ext_vector_type(4))) float f32x4;

__device__ __forceinline__ unsigned short f2bf(float f) {
  union { float f; unsigned u; } v; v.f = f;
  unsigned r = (v.u + 0x7fffu + ((v.u >> 16) & 1u)) >> 16;  // RNE
  return (unsigned short)r;
}
__device__ __forceinline__ float bf2f(unsigned short h) {
  union { unsigned u; float f; } v; v.u = ((unsigned)h) << 16;
  return v.f;
}

__global__ __launch_bounds__(256) void cvt_bf16(const float* __restrict__ in,
                                                unsigned short* __restrict__ out, int n) {
  int i = (blockIdx.x * 256 + threadIdx.x) * 4;
  if (i >= n) return;
  float4 v = *(const float4*)(in + i);
  ushort4 o;
  o.x = f2bf(v.x); o.y = f2bf(v.y); o.z = f2bf(v.z); o.w = f2bf(v.w);
  *(ushort4*)(out + i) = o;
}

// C[m][n] = sum_k A[m][k]*B[n][k] + b_ih[n] + b_hh[n], stored bf16.
// A: [32768][512] bf16 (x), B: [2048][512] bf16 (W_ih). 128x128 tile, BK=32.
__global__ __launch_bounds__(256) void gemm_xg(const unsigned short* __restrict__ A,
                                               const unsigned short* __restrict__ Bw,
                                               const float* __restrict__ b_ih,
                                               const float* __restrict__ b_hh,
                                               unsigned short* __restrict__ xg) {
  __shared__ unsigned short Asub[128][32];
  __shared__ unsigned short Bsub[128][32];
  const int tid = threadIdx.x;
  const int mb = blockIdx.x >> 4;   // 256 M-blocks
  const int nb = blockIdx.x & 15;   // 16 N-blocks
  const int wv = tid >> 6, ln = tid & 63;
  const int wr = wv >> 1, wc = wv & 1;      // 2x2 waves -> 64x64 each
  const int lrow = tid >> 1;                // staging row 0..127
  const int lseg = (tid & 1) * 16;          // bf16 elems 0 or 16

  const unsigned short* Ag = A + (size_t)(mb * 128 + lrow) * 512 + lseg;
  const unsigned short* Bg = Bw + (size_t)(nb * 128 + lrow) * 512 + lseg;

  f32x4 acc[4][4] = {};
  const int frow = ln & 15;           // fragment row (m or n within 16)
  const int kq = (ln >> 4) * 8;       // k-quad offset

  for (int k0 = 0; k0 < 512; k0 += 32) {
    uint4 a0 = *(const uint4*)(Ag + k0);
    uint4 a1 = *(const uint4*)(Ag + k0 + 8);
    uint4 b0 = *(const uint4*)(Bg + k0);
    uint4 b1 = *(const uint4*)(Bg + k0 + 8);
    __syncthreads();  // WAR: previous iteration's fragment reads done
    *(uint4*)&Asub[lrow][lseg]     = a0;
    *(uint4*)&Asub[lrow][lseg + 8] = a1;
    *(uint4*)&Bsub[lrow][lseg]     = b0;
    *(uint4*)&Bsub[lrow][lseg + 8] = b1;
    __syncthreads();
    bf16x8 af[4], bfr[4];
#pragma unroll
    for (int mi = 0; mi < 4; ++mi)
      af[mi] = *(const bf16x8*)&Asub[wr * 64 + mi * 16 + frow][kq];
#pragma unroll
    for (int ni = 0; ni < 4; ++ni)
      bfr[ni] = *(const bf16x8*)&Bsub[wc * 64 + ni * 16 + frow][kq];
#pragma unroll
    for (int mi = 0; mi < 4; ++mi)
#pragma unroll
      for (int ni = 0; ni < 4; ++ni)
        acc[mi][ni] = __builtin_amdgcn_mfma_f32_16x16x32_bf16(af[mi], bfr[ni], acc[mi][ni], 0, 0, 0);
  }

  const int col0 = nb * 128 + wc * 64 + frow;
  float bias[4];
#pragma unroll
  for (int ni = 0; ni < 4; ++ni)
    bias[ni] = b_ih[col0 + ni * 16] + b_hh[col0 + ni * 16];

#pragma unroll
  for (int mi = 0; mi < 4; ++mi) {
    const int m0 = mb * 128 + wr * 64 + mi * 16 + (ln >> 4) * 4;  // D row = quad*4+reg
#pragma unroll
    for (int ni = 0; ni < 4; ++ni) {
#pragma unroll
      for (int rr = 0; rr < 4; ++rr) {
        float v = acc[mi][ni][rr] + bias[ni];
        xg[(size_t)(m0 + rr) * 2048 + col0 + ni * 16] = f2bf(v);  // D col = lane&15
      }
    }
  }
}

// Persistent recurrent kernel. Grid = 256 WGs (8 groups x 32), 256 threads.
// Group g owns batches [4g,4g+4); WG w owns h-indices [16w,16w+16) i.e. 64 gate
// rows {gate*512 + 16w + j}. Thread (kc=tid>>6, r=tid&63) holds
// W_hh[row(r)][kc*128 .. +128) in registers.
__global__ __launch_bounds__(256) void lstm_rec(const unsigned short* __restrict__ xg,
                                                const float* __restrict__ W_hh,
                                                const float* __restrict__ h0,
                                                const float* __restrict__ c0,
                                                float* __restrict__ out,
                                                float* __restrict__ hn,
                                                float* __restrict__ cn,
                                                float* h_buf,        // [2][32][512]
                                                unsigned int* cnt) { // [8]
  __shared__ float h_lds[2048];          // [b][k] for the group's 4 batches
  __shared__ float scratch[64 * 17];     // [r][b*4+kc], padded row stride 17
  __shared__ float gates_lds[64 * 5];    // [r][b], padded row stride 5
  __shared__ float c_lds[64];            // [b*16+j]

  const int tid = threadIdx.x;
  const int g = blockIdx.x >> 5;
  const int w = blockIdx.x & 31;
  const int gb0 = g * 4;
  const int kc = tid >> 6;               // k-chunk (and b in reduce phase)
  const int r = tid & 63;                // local gate row
  const int grow = (r >> 4) * 512 + w * 16 + (r & 15);  // global gate row
  const int kcb = kc * 128;

  // Load W_hh slice into registers (one-time).
  float W[128];
  {
    const float* wp = W_hh + (size_t)grow * 512 + kcb;
#pragma unroll
    for (int i = 0; i < 128; i += 4) {
      float4 v = *(const float4*)(wp + i);
      W[i] = v.x; W[i + 1] = v.y; W[i + 2] = v.z; W[i + 3] = v.w;
    }
  }

  // Stage h0 -> LDS, c0 -> LDS.
  {
    const float* hp = h0 + gb0 * 512 + tid * 8;
    float4 va = *(const float4*)hp;
    float4 vb = *(const float4*)(hp + 4);
    *(float4*)&h_lds[tid * 8] = va;
    *(float4*)&h_lds[tid * 8 + 4] = vb;
    if (tid < 64) {
      int jj = tid & 15, bb = tid >> 4;
      c_lds[bb * 16 + jj] = c0[(gb0 + bb) * 512 + w * 16 + jj];
    }
  }
  __syncthreads();

  for (int t = 0; t < 1024; ++t) {
    // xg value for this thread's reduce role (b=kc, row=r); latency hidden by FMA loop.
    float xg_v = bf2f(xg[(size_t)((gb0 + kc) * 1024 + t) * 2048 + grow]);

    // Main FMA: acc[b] += W[row][kc*128+i] * h[b][kc*128+i]
    float acc0 = 0.f, acc1 = 0.f, acc2 = 0.f, acc3 = 0.f;
#pragma unroll
    for (int i = 0; i < 128; i += 4) {
      float4 ha = *(const float4*)&h_lds[kcb + i];
      float4 hb = *(const float4*)&h_lds[512 + kcb + i];
      float4 hc = *(const float4*)&h_lds[1024 + kcb + i];
      float4 hd = *(const float4*)&h_lds[1536 + kcb + i];
      acc0 = fmaf(W[i], ha.x, acc0); acc0 = fmaf(W[i + 1], ha.y, acc0);
      acc0 = fmaf(W[i + 2], ha.z, acc0); acc0 = fmaf(W[i + 3], ha.w, acc0);
      acc1 = fmaf(W[i], hb.x, acc1); acc1 = fmaf(W[i + 1], hb.y, acc1);
      acc1 = fmaf(W[i + 2], hb.z, acc1); acc1 = fmaf(W[i + 3], hb.w, acc1);
      acc2 = fmaf(W[i], hc.x, acc2); acc2 = fmaf(W[i + 1], hc.y, acc2);
      acc2 = fmaf(W[i + 2], hc.z, acc2); acc2 = fmaf(W[i + 3], hc.w, acc2);
      acc3 = fmaf(W[i], hd.x, acc3); acc3 = fmaf(W[i + 1], hd.y, acc3);
      acc3 = fmaf(W[i + 2], hd.z, acc3); acc3 = fmaf(W[i + 3], hd.w, acc3);
    }
    scratch[r * 17 + kc] = acc0;
    scratch[r * 17 + 4 + kc] = acc1;
    scratch[r * 17 + 8 + kc] = acc2;
    scratch[r * 17 + 12 + kc] = acc3;
    __syncthreads();

    // Reduce over k-chunks; this thread acts as (b=kc, row=r).
    {
      float s = xg_v + scratch[r * 17 + kc * 4] + scratch[r * 17 + kc * 4 + 1]
                     + scratch[r * 17 + kc * 4 + 2] + scratch[r * 17 + kc * 4 + 3];
      gates_lds[r * 5 + kc] = s;
    }
    __syncthreads();

    // Activation + state update on 64 threads (j, b).
    if (tid < 64) {
      const int jj = tid & 15, bb = tid >> 4;
      float gi = gates_lds[jj * 5 + bb];
      float gf = gates_lds[(16 + jj) * 5 + bb];
      float gc = gates_lds[(32 + jj) * 5 + bb];
      float go = gates_lds[(48 + jj) * 5 + bb];
      float ig = 1.f / (1.f + __expf(-gi));
      float fg = 1.f / (1.f + __expf(-gf));
      float gt = tanhf(gc);
      float og = 1.f / (1.f + __expf(-go));
      float c = fmaf(fg, c_lds[bb * 16 + jj], ig * gt);
      c_lds[bb * 16 + jj] = c;
      float hv = og * tanhf(c);
      out[(size_t)((gb0 + bb) * 1024 + t) * 512 + w * 16 + jj] = hv;
      __hip_atomic_store(&h_buf[((t + 1) & 1) * 16384 + (gb0 + bb) * 512 + w * 16 + jj], hv,
                         __ATOMIC_RELAXED, __HIP_MEMORY_SCOPE_AGENT);
      if (t == 1023) {
        hn[(gb0 + bb) * 512 + w * 16 + jj] = hv;
        cn[(gb0 + bb) * 512 + w * 16 + jj] = c;
      }
    }
    __syncthreads();  // drains vmcnt: agent-scope h stores are globally visible

    if (t < 1023) {
      if (tid == 0) {
        __hip_atomic_fetch_add(&cnt[g], 1u, __ATOMIC_RELEASE, __HIP_MEMORY_SCOPE_AGENT);
        const unsigned target = 32u * (unsigned)(t + 1);
        while (__hip_atomic_load(&cnt[g], __ATOMIC_ACQUIRE, __HIP_MEMORY_SCOPE_AGENT) < target)
          __builtin_amdgcn_s_sleep(2);
      }
      __syncthreads();
      // Stage next h (parity (t+1)&1) into LDS with coherent (L1/L2-bypass) loads.
      float* hb = h_buf + ((t + 1) & 1) * 16384 + gb0 * 512 + tid * 8;
      float v[8];
#pragma unroll
      for (int q = 0; q < 8; ++q)
        v[q] = __hip_atomic_load(hb + q, __ATOMIC_RELAXED, __HIP_MEMORY_SCOPE_AGENT);
#pragma unroll
      for (int q = 0; q < 8; ++q) h_lds[tid * 8 + q] = v[q];
      __syncthreads();
    }
  }
}

extern "C" void kernel_launch(void* const* d_in, const int* in_sizes, int n_in,
                              void* d_out, int out_size, void* d_ws, size_t ws_size,
                              hipStream_t stream) {
  const float* x    = (const float*)d_in[0];
  const float* W_ih = (const float*)d_in[1];
  const float* W_hh = (const float*)d_in[2];
  const float* b_ih = (const float*)d_in[3];
  const float* b_hh = (const float*)d_in[4];
  const float* h0   = (const float*)d_in[5];
  const float* c0   = (const float*)d_in[6];
  float* out = (float*)d_out;
  float* hn = out + (size_t)32 * 1024 * 512;   // 16777216
  float* cn = hn + 32 * 512;

  uint8_t* ws = (uint8_t*)d_ws;
  unsigned short* xg   = (unsigned short*)ws;                   // 134,217,728 B
  unsigned short* x_bf = (unsigned short*)(ws + 134217728u);    //  33,554,432 B
  unsigned short* w_bf = (unsigned short*)(ws + 167772160u);    //   2,097,152 B
  float* h_buf         = (float*)(ws + 169869312u);             //     131,072 B
  unsigned int* cnt    = (unsigned int*)(ws + 170000384u);      //          64 B

  hipMemsetAsync(cnt, 0, 64, stream);  // ws is poisoned 0xAA before every launch
  cvt_bf16<<<dim3(16384), dim3(256), 0, stream>>>(x, x_bf, 16777216);
  cvt_bf16<<<dim3(1024), dim3(256), 0, stream>>>(W_ih, w_bf, 1048576);
  gemm_xg<<<dim3(4096), dim3(256), 0, stream>>>(x_bf, w_bf, b_ih, b_hh, xg);

  void* args[] = {(void*)&xg, (void*)&W_hh, (void*)&h0, (void*)&c0,
                  (void*)&out, (void*)&hn, (void*)&cn, (void*)&h_buf, (void*)&cnt};
  hipLaunchCooperativeKernel((const void*)lstm_rec, dim3(256), dim3(256), args, 0, stream);
}

// Round 2
// 4614.060 us; speedup vs baseline: 4.2075x; 4.2075x over previous
//
#include <hip/hip_runtime.h>
#include <stdint.h>

// LSTM: B=32, S=1024, I=H=512, 4H=2048
// Phase 1: x_gates = x @ W_ih^T + (b_ih + b_hh)   [bf16 MFMA GEMM]
// Phase 2: persistent cooperative kernel, 8 groups x 32 WGs; W_hh slice in
//          REGISTERS (128 fp32/thr; __launch_bounds__(256,1) so it is NOT
//          spilled — round-1 VGPR=92 proved spilling), h in LDS, h exchanged
//          via global double buffer + per-group padded counter, all RELAXED
//          agent-scope atomics (acquire/release emit L2 cache-maintenance ops
//          on multi-XCD gfx950; ordering comes from __syncthreads vmcnt drain).

typedef __attribute__((ext_vector_type(8))) short bf16x8;
typedef __attribute__((ext_vector_type(4))) float f32x4;

__device__ __forceinline__ unsigned short f2bf(float f) {
  union { float f; unsigned u; } v; v.f = f;
  unsigned r = (v.u + 0x7fffu + ((v.u >> 16) & 1u)) >> 16;  // RNE
  return (unsigned short)r;
}
__device__ __forceinline__ float bf2f(unsigned short h) {
  union { unsigned u; float f; } v; v.u = ((unsigned)h) << 16;
  return v.f;
}

__global__ __launch_bounds__(256) void cvt_bf16(const float* __restrict__ in,
                                                unsigned short* __restrict__ out, int n) {
  int i = (blockIdx.x * 256 + threadIdx.x) * 4;
  if (i >= n) return;
  float4 v = *(const float4*)(in + i);
  ushort4 o;
  o.x = f2bf(v.x); o.y = f2bf(v.y); o.z = f2bf(v.z); o.w = f2bf(v.w);
  *(ushort4*)(out + i) = o;
}

// C[m][n] = sum_k A[m][k]*B[n][k] + b_ih[n] + b_hh[n], stored bf16.
// A: [32768][512] bf16 (x), B: [2048][512] bf16 (W_ih). 128x128 tile, BK=32.
__global__ __launch_bounds__(256) void gemm_xg(const unsigned short* __restrict__ A,
                                               const unsigned short* __restrict__ Bw,
                                               const float* __restrict__ b_ih,
                                               const float* __restrict__ b_hh,
                                               unsigned short* __restrict__ xg) {
  __shared__ unsigned short Asub[128][32];
  __shared__ unsigned short Bsub[128][32];
  const int tid = threadIdx.x;
  const int mb = blockIdx.x >> 4;
  const int nb = blockIdx.x & 15;
  const int wv = tid >> 6, ln = tid & 63;
  const int wr = wv >> 1, wc = wv & 1;
  const int lrow = tid >> 1;
  const int lseg = (tid & 1) * 16;

  const unsigned short* Ag = A + (size_t)(mb * 128 + lrow) * 512 + lseg;
  const unsigned short* Bg = Bw + (size_t)(nb * 128 + lrow) * 512 + lseg;

  f32x4 acc[4][4] = {};
  const int frow = ln & 15;
  const int kq = (ln >> 4) * 8;

  for (int k0 = 0; k0 < 512; k0 += 32) {
    uint4 a0 = *(const uint4*)(Ag + k0);
    uint4 a1 = *(const uint4*)(Ag + k0 + 8);
    uint4 b0 = *(const uint4*)(Bg + k0);
    uint4 b1 = *(const uint4*)(Bg + k0 + 8);
    __syncthreads();
    *(uint4*)&Asub[lrow][lseg]     = a0;
    *(uint4*)&Asub[lrow][lseg + 8] = a1;
    *(uint4*)&Bsub[lrow][lseg]     = b0;
    *(uint4*)&Bsub[lrow][lseg + 8] = b1;
    __syncthreads();
    bf16x8 af[4], bfr[4];
#pragma unroll
    for (int mi = 0; mi < 4; ++mi)
      af[mi] = *(const bf16x8*)&Asub[wr * 64 + mi * 16 + frow][kq];
#pragma unroll
    for (int ni = 0; ni < 4; ++ni)
      bfr[ni] = *(const bf16x8*)&Bsub[wc * 64 + ni * 16 + frow][kq];
#pragma unroll
    for (int mi = 0; mi < 4; ++mi)
#pragma unroll
      for (int ni = 0; ni < 4; ++ni)
        acc[mi][ni] = __builtin_amdgcn_mfma_f32_16x16x32_bf16(af[mi], bfr[ni], acc[mi][ni], 0, 0, 0);
  }

  const int col0 = nb * 128 + wc * 64 + frow;
  float bias[4];
#pragma unroll
  for (int ni = 0; ni < 4; ++ni)
    bias[ni] = b_ih[col0 + ni * 16] + b_hh[col0 + ni * 16];

#pragma unroll
  for (int mi = 0; mi < 4; ++mi) {
    const int m0 = mb * 128 + wr * 64 + mi * 16 + (ln >> 4) * 4;
#pragma unroll
    for (int ni = 0; ni < 4; ++ni) {
#pragma unroll
      for (int rr = 0; rr < 4; ++rr) {
        float v = acc[mi][ni][rr] + bias[ni];
        xg[(size_t)(m0 + rr) * 2048 + col0 + ni * 16] = f2bf(v);
      }
    }
  }
}

// Persistent recurrent kernel. Grid = 256 WGs (8 groups x 32), 256 threads.
// Group g owns batches [4g,4g+4); WG w owns h-indices [16w,16w+16).
// Thread (kc=tid>>6, r=tid&63) holds W_hh[row(r)][kc*128 .. +128) in registers.
__global__ __launch_bounds__(256, 1) void lstm_rec(const unsigned short* __restrict__ xg,
                                                   const float* __restrict__ W_hh,
                                                   const float* __restrict__ h0,
                                                   const float* __restrict__ c0,
                                                   float* __restrict__ out,
                                                   float* __restrict__ hn,
                                                   float* __restrict__ cn,
                                                   float* h_buf,        // [2][32][512]
                                                   unsigned int* cnt) { // [8], stride 64 uints
  __shared__ float h_lds[2048];
  __shared__ float scratch[64 * 17];
  __shared__ float gates_lds[64 * 5];
  __shared__ float c_lds[64];

  const int tid = threadIdx.x;
  const int g = blockIdx.x >> 5;
  const int w = blockIdx.x & 31;
  const int gb0 = g * 4;
  const int kc = tid >> 6;
  const int r = tid & 63;
  const int grow = (r >> 4) * 512 + w * 16 + (r & 15);
  const int kcb = kc * 128;
  unsigned int* my_cnt = cnt + g * 64;  // 256B stride: no false sharing

  float W[128];
  {
    const float* wp = W_hh + (size_t)grow * 512 + kcb;
#pragma unroll
    for (int i = 0; i < 128; i += 4) {
      float4 v = *(const float4*)(wp + i);
      W[i] = v.x; W[i + 1] = v.y; W[i + 2] = v.z; W[i + 3] = v.w;
    }
  }

  {
    const float* hp = h0 + gb0 * 512 + tid * 8;
    float4 va = *(const float4*)hp;
    float4 vb = *(const float4*)(hp + 4);
    *(float4*)&h_lds[tid * 8] = va;
    *(float4*)&h_lds[tid * 8 + 4] = vb;
    if (tid < 64) {
      int jj = tid & 15, bb = tid >> 4;
      c_lds[bb * 16 + jj] = c0[(gb0 + bb) * 512 + w * 16 + jj];
    }
  }
  __syncthreads();

  for (int t = 0; t < 1024; ++t) {
    float xg_v = bf2f(xg[(size_t)((gb0 + kc) * 1024 + t) * 2048 + grow]);

    float acc0 = 0.f, acc1 = 0.f, acc2 = 0.f, acc3 = 0.f;
#pragma unroll
    for (int i = 0; i < 128; i += 4) {
      float4 ha = *(const float4*)&h_lds[kcb + i];
      float4 hb = *(const float4*)&h_lds[512 + kcb + i];
      float4 hc = *(const float4*)&h_lds[1024 + kcb + i];
      float4 hd = *(const float4*)&h_lds[1536 + kcb + i];
      acc0 = fmaf(W[i], ha.x, acc0); acc0 = fmaf(W[i + 1], ha.y, acc0);
      acc0 = fmaf(W[i + 2], ha.z, acc0); acc0 = fmaf(W[i + 3], ha.w, acc0);
      acc1 = fmaf(W[i], hb.x, acc1); acc1 = fmaf(W[i + 1], hb.y, acc1);
      acc1 = fmaf(W[i + 2], hb.z, acc1); acc1 = fmaf(W[i + 3], hb.w, acc1);
      acc2 = fmaf(W[i], hc.x, acc2); acc2 = fmaf(W[i + 1], hc.y, acc2);
      acc2 = fmaf(W[i + 2], hc.z, acc2); acc2 = fmaf(W[i + 3], hc.w, acc2);
      acc3 = fmaf(W[i], hd.x, acc3); acc3 = fmaf(W[i + 1], hd.y, acc3);
      acc3 = fmaf(W[i + 2], hd.z, acc3); acc3 = fmaf(W[i + 3], hd.w, acc3);
    }
    scratch[r * 17 + kc] = acc0;
    scratch[r * 17 + 4 + kc] = acc1;
    scratch[r * 17 + 8 + kc] = acc2;
    scratch[r * 17 + 12 + kc] = acc3;
    __syncthreads();

    {
      float s = xg_v + scratch[r * 17 + kc * 4] + scratch[r * 17 + kc * 4 + 1]
                     + scratch[r * 17 + kc * 4 + 2] + scratch[r * 17 + kc * 4 + 3];
      gates_lds[r * 5 + kc] = s;
    }
    __syncthreads();

    if (tid < 64) {
      const int jj = tid & 15, bb = tid >> 4;
      float gi = gates_lds[jj * 5 + bb];
      float gf = gates_lds[(16 + jj) * 5 + bb];
      float gc = gates_lds[(32 + jj) * 5 + bb];
      float go = gates_lds[(48 + jj) * 5 + bb];
      float ig = 1.f / (1.f + __expf(-gi));
      float fg = 1.f / (1.f + __expf(-gf));
      float gt = tanhf(gc);
      float og = 1.f / (1.f + __expf(-go));
      float c = fmaf(fg, c_lds[bb * 16 + jj], ig * gt);
      c_lds[bb * 16 + jj] = c;
      float hv = og * tanhf(c);
      out[(size_t)((gb0 + bb) * 1024 + t) * 512 + w * 16 + jj] = hv;
      __hip_atomic_store(&h_buf[((t + 1) & 1) * 16384 + (gb0 + bb) * 512 + w * 16 + jj], hv,
                         __ATOMIC_RELAXED, __HIP_MEMORY_SCOPE_AGENT);
      if (t == 1023) {
        hn[(gb0 + bb) * 512 + w * 16 + jj] = hv;
        cn[(gb0 + bb) * 512 + w * 16 + jj] = c;
      }
    }
    __syncthreads();  // emits s_waitcnt vmcnt(0) before s_barrier: h stores are at LLC

    if (t < 1023) {
      if (tid == 0) {
        __hip_atomic_fetch_add(my_cnt, 1u, __ATOMIC_RELAXED, __HIP_MEMORY_SCOPE_AGENT);
        const unsigned target = 32u * (unsigned)(t + 1);
        while (__hip_atomic_load(my_cnt, __ATOMIC_RELAXED, __HIP_MEMORY_SCOPE_AGENT) < target)
          __builtin_amdgcn_s_sleep(2);
      }
      __syncthreads();
      float* hb = h_buf + ((t + 1) & 1) * 16384 + gb0 * 512 + tid * 8;
      float v[8];
#pragma unroll
      for (int q = 0; q < 8; ++q)
        v[q] = __hip_atomic_load(hb + q, __ATOMIC_RELAXED, __HIP_MEMORY_SCOPE_AGENT);
#pragma unroll
      for (int q = 0; q < 8; ++q) h_lds[tid * 8 + q] = v[q];
      __syncthreads();
    }
  }
}

extern "C" void kernel_launch(void* const* d_in, const int* in_sizes, int n_in,
                              void* d_out, int out_size, void* d_ws, size_t ws_size,
                              hipStream_t stream) {
  const float* x    = (const float*)d_in[0];
  const float* W_ih = (const float*)d_in[1];
  const float* W_hh = (const float*)d_in[2];
  const float* b_ih = (const float*)d_in[3];
  const float* b_hh = (const float*)d_in[4];
  const float* h0   = (const float*)d_in[5];
  const float* c0   = (const float*)d_in[6];
  float* out = (float*)d_out;
  float* hn = out + (size_t)32 * 1024 * 512;
  float* cn = hn + 32 * 512;

  uint8_t* ws = (uint8_t*)d_ws;
  unsigned short* xg   = (unsigned short*)ws;                   // 134,217,728 B
  unsigned short* x_bf = (unsigned short*)(ws + 134217728u);    //  33,554,432 B
  unsigned short* w_bf = (unsigned short*)(ws + 167772160u);    //   2,097,152 B
  float* h_buf         = (float*)(ws + 169869312u);             //     131,072 B
  unsigned int* cnt    = (unsigned int*)(ws + 170000384u);      //  8 * 256 B

  hipMemsetAsync(cnt, 0, 8 * 256, stream);
  cvt_bf16<<<dim3(16384), dim3(256), 0, stream>>>(x, x_bf, 16777216);
  cvt_bf16<<<dim3(1024), dim3(256), 0, stream>>>(W_ih, w_bf, 1048576);
  gemm_xg<<<dim3(4096), dim3(256), 0, stream>>>(x_bf, w_bf, b_ih, b_hh, xg);

  void* args[] = {(void*)&xg, (void*)&W_hh, (void*)&h0, (void*)&c0,
                  (void*)&out, (void*)&hn, (void*)&cn, (void*)&h_buf, (void*)&cnt};
  hipLaunchCooperativeKernel((const void*)lstm_rec, dim3(256), dim3(256), args, 0, stream);
}

// Round 3
// 3894.181 us; speedup vs baseline: 4.9853x; 1.1849x over previous
//
#include <hip/hip_runtime.h>
#include <stdint.h>

// LSTM: B=32, S=1024, I=H=512, 4H=2048
// Phase 1: x_gates = x @ W_ih^T + (b_ih + b_hh)   [bf16 MFMA GEMM]
// Phase 2: persistent cooperative kernel, 8 groups x 32 WGs; W_hh slice in
//          REGISTERS (pinned via asm "+v" barrier — round-2 showed the
//          compiler sinks the loads into the t-loop otherwise: VGPR=92,
//          FETCH=531MB), h in LDS, h exchanged via global double buffer +
//          per-group padded counter, all RELAXED agent-scope atomics
//          (ordering comes from __syncthreads' vmcnt(0) drain).

typedef __attribute__((ext_vector_type(8))) short bf16x8;
typedef __attribute__((ext_vector_type(4))) float f32x4;

__device__ __forceinline__ unsigned short f2bf(float f) {
  union { float f; unsigned u; } v; v.f = f;
  unsigned r = (v.u + 0x7fffu + ((v.u >> 16) & 1u)) >> 16;  // RNE
  return (unsigned short)r;
}
__device__ __forceinline__ float bf2f(unsigned short h) {
  union { unsigned u; float f; } v; v.u = ((unsigned)h) << 16;
  return v.f;
}

__global__ __launch_bounds__(256) void cvt_bf16(const float* __restrict__ in,
                                                unsigned short* __restrict__ out, int n) {
  int i = (blockIdx.x * 256 + threadIdx.x) * 4;
  if (i >= n) return;
  float4 v = *(const float4*)(in + i);
  ushort4 o;
  o.x = f2bf(v.x); o.y = f2bf(v.y); o.z = f2bf(v.z); o.w = f2bf(v.w);
  *(ushort4*)(out + i) = o;
}

// C[m][n] = sum_k A[m][k]*B[n][k] + b_ih[n] + b_hh[n], stored bf16.
__global__ __launch_bounds__(256) void gemm_xg(const unsigned short* __restrict__ A,
                                               const unsigned short* __restrict__ Bw,
                                               const float* __restrict__ b_ih,
                                               const float* __restrict__ b_hh,
                                               unsigned short* __restrict__ xg) {
  __shared__ unsigned short Asub[128][32];
  __shared__ unsigned short Bsub[128][32];
  const int tid = threadIdx.x;
  const int mb = blockIdx.x >> 4;
  const int nb = blockIdx.x & 15;
  const int wv = tid >> 6, ln = tid & 63;
  const int wr = wv >> 1, wc = wv & 1;
  const int lrow = tid >> 1;
  const int lseg = (tid & 1) * 16;

  const unsigned short* Ag = A + (size_t)(mb * 128 + lrow) * 512 + lseg;
  const unsigned short* Bg = Bw + (size_t)(nb * 128 + lrow) * 512 + lseg;

  f32x4 acc[4][4] = {};
  const int frow = ln & 15;
  const int kq = (ln >> 4) * 8;

  for (int k0 = 0; k0 < 512; k0 += 32) {
    uint4 a0 = *(const uint4*)(Ag + k0);
    uint4 a1 = *(const uint4*)(Ag + k0 + 8);
    uint4 b0 = *(const uint4*)(Bg + k0);
    uint4 b1 = *(const uint4*)(Bg + k0 + 8);
    __syncthreads();
    *(uint4*)&Asub[lrow][lseg]     = a0;
    *(uint4*)&Asub[lrow][lseg + 8] = a1;
    *(uint4*)&Bsub[lrow][lseg]     = b0;
    *(uint4*)&Bsub[lrow][lseg + 8] = b1;
    __syncthreads();
    bf16x8 af[4], bfr[4];
#pragma unroll
    for (int mi = 0; mi < 4; ++mi)
      af[mi] = *(const bf16x8*)&Asub[wr * 64 + mi * 16 + frow][kq];
#pragma unroll
    for (int ni = 0; ni < 4; ++ni)
      bfr[ni] = *(const bf16x8*)&Bsub[wc * 64 + ni * 16 + frow][kq];
#pragma unroll
    for (int mi = 0; mi < 4; ++mi)
#pragma unroll
      for (int ni = 0; ni < 4; ++ni)
        acc[mi][ni] = __builtin_amdgcn_mfma_f32_16x16x32_bf16(af[mi], bfr[ni], acc[mi][ni], 0, 0, 0);
  }

  const int col0 = nb * 128 + wc * 64 + frow;
  float bias[4];
#pragma unroll
  for (int ni = 0; ni < 4; ++ni)
    bias[ni] = b_ih[col0 + ni * 16] + b_hh[col0 + ni * 16];

#pragma unroll
  for (int mi = 0; mi < 4; ++mi) {
    const int m0 = mb * 128 + wr * 64 + mi * 16 + (ln >> 4) * 4;
#pragma unroll
    for (int ni = 0; ni < 4; ++ni) {
#pragma unroll
      for (int rr = 0; rr < 4; ++rr) {
        float v = acc[mi][ni][rr] + bias[ni];
        xg[(size_t)(m0 + rr) * 2048 + col0 + ni * 16] = f2bf(v);
      }
    }
  }
}

// Persistent recurrent kernel. Grid = 256 WGs (8 groups x 32), 256 threads.
// Group g owns batches [4g,4g+4); WG w owns h-indices [16w,16w+16).
// Thread (kc=tid>>6, r=tid&63) holds W_hh[row(r)][kc*128 .. +128) in registers.
__global__ __launch_bounds__(256, 1) void lstm_rec(const unsigned short* __restrict__ xg,
                                                   const float* __restrict__ W_hh,
                                                   const float* __restrict__ h0,
                                                   const float* __restrict__ c0,
                                                   float* __restrict__ out,
                                                   float* __restrict__ hn,
                                                   float* __restrict__ cn,
                                                   float* h_buf,        // [2][32][512]
                                                   unsigned int* cnt) { // [8], stride 64 uints
  __shared__ float h_lds[2048];
  __shared__ float scratch[64 * 17];
  __shared__ float gates_lds[64 * 5];
  __shared__ float c_lds[64];

  const int tid = threadIdx.x;
  const int g = blockIdx.x >> 5;
  const int w = blockIdx.x & 31;
  const int gb0 = g * 4;
  const int kc = tid >> 6;
  const int r = tid & 63;
  const int grow = (r >> 4) * 512 + w * 16 + (r & 15);
  const int kcb = kc * 128;
  unsigned int* my_cnt = cnt + g * 64;  // 256B stride: no false sharing

  // One-time W_hh slice load, then PIN in VGPRs: the "+v" asm makes each
  // element an opaque register value the compiler cannot re-load per step.
  float W[128];
  {
    const float* wp = W_hh + (size_t)grow * 512 + kcb;
#pragma unroll
    for (int i = 0; i < 128; i += 4) {
      float4 v = *(const float4*)(wp + i);
      W[i] = v.x; W[i + 1] = v.y; W[i + 2] = v.z; W[i + 3] = v.w;
    }
  }
#pragma unroll
  for (int i = 0; i < 128; ++i) asm volatile("" : "+v"(W[i]));

  {
    const float* hp = h0 + gb0 * 512 + tid * 8;
    float4 va = *(const float4*)hp;
    float4 vb = *(const float4*)(hp + 4);
    *(float4*)&h_lds[tid * 8] = va;
    *(float4*)&h_lds[tid * 8 + 4] = vb;
    if (tid < 64) {
      int jj = tid & 15, bb = tid >> 4;
      c_lds[bb * 16 + jj] = c0[(gb0 + bb) * 512 + w * 16 + jj];
    }
  }
  __syncthreads();

  for (int t = 0; t < 1024; ++t) {
    // Issued at loop top, consumed after the FMA loop -> latency hidden.
    float xg_v = bf2f(xg[(size_t)((gb0 + kc) * 1024 + t) * 2048 + grow]);

    float acc0 = 0.f, acc1 = 0.f, acc2 = 0.f, acc3 = 0.f;
#pragma unroll
    for (int i = 0; i < 128; i += 4) {
      float4 ha = *(const float4*)&h_lds[kcb + i];
      float4 hb = *(const float4*)&h_lds[512 + kcb + i];
      float4 hc = *(const float4*)&h_lds[1024 + kcb + i];
      float4 hd = *(const float4*)&h_lds[1536 + kcb + i];
      acc0 = fmaf(W[i], ha.x, acc0); acc0 = fmaf(W[i + 1], ha.y, acc0);
      acc0 = fmaf(W[i + 2], ha.z, acc0); acc0 = fmaf(W[i + 3], ha.w, acc0);
      acc1 = fmaf(W[i], hb.x, acc1); acc1 = fmaf(W[i + 1], hb.y, acc1);
      acc1 = fmaf(W[i + 2], hb.z, acc1); acc1 = fmaf(W[i + 3], hb.w, acc1);
      acc2 = fmaf(W[i], hc.x, acc2); acc2 = fmaf(W[i + 1], hc.y, acc2);
      acc2 = fmaf(W[i + 2], hc.z, acc2); acc2 = fmaf(W[i + 3], hc.w, acc2);
      acc3 = fmaf(W[i], hd.x, acc3); acc3 = fmaf(W[i + 1], hd.y, acc3);
      acc3 = fmaf(W[i + 2], hd.z, acc3); acc3 = fmaf(W[i + 3], hd.w, acc3);
    }
    scratch[r * 17 + kc] = acc0;
    scratch[r * 17 + 4 + kc] = acc1;
    scratch[r * 17 + 8 + kc] = acc2;
    scratch[r * 17 + 12 + kc] = acc3;
    __syncthreads();

    {
      float s = xg_v + scratch[r * 17 + kc * 4] + scratch[r * 17 + kc * 4 + 1]
                     + scratch[r * 17 + kc * 4 + 2] + scratch[r * 17 + kc * 4 + 3];
      gates_lds[r * 5 + kc] = s;
    }
    __syncthreads();

    if (tid < 64) {
      const int jj = tid & 15, bb = tid >> 4;
      float gi = gates_lds[jj * 5 + bb];
      float gf = gates_lds[(16 + jj) * 5 + bb];
      float gc = gates_lds[(32 + jj) * 5 + bb];
      float go = gates_lds[(48 + jj) * 5 + bb];
      float ig = 1.f / (1.f + __expf(-gi));
      float fg = 1.f / (1.f + __expf(-gf));
      float gt = tanhf(gc);
      float og = 1.f / (1.f + __expf(-go));
      float c = fmaf(fg, c_lds[bb * 16 + jj], ig * gt);
      c_lds[bb * 16 + jj] = c;
      float hv = og * tanhf(c);
      out[(size_t)((gb0 + bb) * 1024 + t) * 512 + w * 16 + jj] = hv;
      __hip_atomic_store(&h_buf[((t + 1) & 1) * 16384 + (gb0 + bb) * 512 + w * 16 + jj], hv,
                         __ATOMIC_RELAXED, __HIP_MEMORY_SCOPE_AGENT);
      if (t == 1023) {
        hn[(gb0 + bb) * 512 + w * 16 + jj] = hv;
        cn[(gb0 + bb) * 512 + w * 16 + jj] = c;
      }
    }
    __syncthreads();  // s_waitcnt vmcnt(0) before s_barrier: h stores are at LLC

    if (t < 1023) {
      if (tid == 0) {
        __hip_atomic_fetch_add(my_cnt, 1u, __ATOMIC_RELAXED, __HIP_MEMORY_SCOPE_AGENT);
        const unsigned target = 32u * (unsigned)(t + 1);
        while (__hip_atomic_load(my_cnt, __ATOMIC_RELAXED, __HIP_MEMORY_SCOPE_AGENT) < target)
          __builtin_amdgcn_s_sleep(2);
      }
      __syncthreads();
      // Stage next h into LDS; 8-byte relaxed atomic loads (4 VMEM ops).
      const unsigned long long* hb =
          (const unsigned long long*)(h_buf + ((t + 1) & 1) * 16384 + gb0 * 512 + tid * 8);
      unsigned long long v[4];
#pragma unroll
      for (int q = 0; q < 4; ++q)
        v[q] = __hip_atomic_load(hb + q, __ATOMIC_RELAXED, __HIP_MEMORY_SCOPE_AGENT);
#pragma unroll
      for (int q = 0; q < 4; ++q)
        *(unsigned long long*)&h_lds[tid * 8 + q * 2] = v[q];
      __syncthreads();
    }
  }
}

extern "C" void kernel_launch(void* const* d_in, const int* in_sizes, int n_in,
                              void* d_out, int out_size, void* d_ws, size_t ws_size,
                              hipStream_t stream) {
  const float* x    = (const float*)d_in[0];
  const float* W_ih = (const float*)d_in[1];
  const float* W_hh = (const float*)d_in[2];
  const float* b_ih = (const float*)d_in[3];
  const float* b_hh = (const float*)d_in[4];
  const float* h0   = (const float*)d_in[5];
  const float* c0   = (const float*)d_in[6];
  float* out = (float*)d_out;
  float* hn = out + (size_t)32 * 1024 * 512;
  float* cn = hn + 32 * 512;

  uint8_t* ws = (uint8_t*)d_ws;
  unsigned short* xg   = (unsigned short*)ws;                   // 134,217,728 B
  unsigned short* x_bf = (unsigned short*)(ws + 134217728u);    //  33,554,432 B
  unsigned short* w_bf = (unsigned short*)(ws + 167772160u);    //   2,097,152 B
  float* h_buf         = (float*)(ws + 169869312u);             //     131,072 B
  unsigned int* cnt    = (unsigned int*)(ws + 170000384u);      //  8 * 256 B

  hipMemsetAsync(cnt, 0, 8 * 256, stream);
  cvt_bf16<<<dim3(16384), dim3(256), 0, stream>>>(x, x_bf, 16777216);
  cvt_bf16<<<dim3(1024), dim3(256), 0, stream>>>(W_ih, w_bf, 1048576);
  gemm_xg<<<dim3(4096), dim3(256), 0, stream>>>(x_bf, w_bf, b_ih, b_hh, xg);

  void* args[] = {(void*)&xg, (void*)&W_hh, (void*)&h0, (void*)&c0,
                  (void*)&out, (void*)&hn, (void*)&cn, (void*)&h_buf, (void*)&cnt};
  hipLaunchCooperativeKernel((const void*)lstm_rec, dim3(256), dim3(256), args, 0, stream);
}